// Round 7
// baseline (155.988 us; speedup 1.0000x reference)
//
#include <hip/hip_runtime.h>
#include <math.h>

#define NB 16          // images
#define NP 100         // predictions per image
#define NT 320         // total targets
#define NCLS 80        // classes
#define WO 128         // output mask width/height
#define HW 16384       // 128*128
#define QT 1600        // NB*NP
#define PI 20          // targets per image
#define KSPLIT 8
#define KSLICE 2048    // HW/KSPLIT  (same slice boundaries as r3/r5/r6 -> bit-identical num)
#define BK 64
#define KTILES 32      // KSLICE/BK
#define SRC_W 256
#define BM 32
#define BN 320
#define CH 16          // output rows per downsample block

typedef _Float16 half8v __attribute__((ext_vector_type(8)));
typedef float f32x4 __attribute__((ext_vector_type(4)));

#define GLOAD_LDS16(gp, lp) __builtin_amdgcn_global_load_lds(                         \
    (const __attribute__((address_space(1))) void*)(gp),                              \
    (__attribute__((address_space(3))) void*)(lp), 16, 0, 0)

__device__ __forceinline__ float sigf(float x){ return 1.0f/(1.0f+expf(-x)); }
__device__ __forceinline__ float sigfast(float x){ return 1.0f/(1.0f+__expf(-x)); }

// jax.image.resize(linear, antialias=True) 2x-downsample weights, 256 -> 128
__device__ __forceinline__ void mkw128(int i, float* w, int* ix){
  int j0 = 2*i - 1;
  ix[0]=j0; ix[1]=j0+1; ix[2]=j0+2; ix[3]=j0+3;
  w[0]=0.125f; w[1]=0.375f; w[2]=0.375f; w[3]=0.125f;
  if (i == 0){ ix[0]=0; w[0]=0.0f; w[1]=3.0f/7.0f; w[2]=3.0f/7.0f; w[3]=1.0f/7.0f; }
  if (i == 127){ ix[3]=255; w[3]=0.0f; w[0]=1.0f/7.0f; w[1]=3.0f/7.0f; w[2]=3.0f/7.0f; }
}

// K1: separable downsample, one block per (target, 16-row output chunk).
__global__ __launch_bounds__(256) void k_downsample(const float* __restrict__ tgt,
                                                    _Float16* __restrict__ tm,
                                                    float* __restrict__ tqpart){
  const int blk = blockIdx.x;
  const int t = blk >> 3;
  const int c = blk & 7;               // chunk: output rows [c*16, c*16+16)
  const int x = threadIdx.x;           // input column 0..255
  const int oy0 = c * CH;
  const int r0 = 2*oy0 - 1;            // first needed input row (may be -1)
  const float* src = tgt + (size_t)t * (SRC_W*SRC_W);
  __shared__ float vbuf[CH][SRC_W];
  __shared__ float wred[4];

  float cc[34];
  #pragma unroll
  for (int li = 0; li < 34; ++li){
    int r = r0 + li; r = r < 0 ? 0 : (r > 255 ? 255 : r);
    cc[li] = src[r*SRC_W + x];
  }
  #pragma unroll
  for (int dy = 0; dy < CH; ++dy){
    int oy = oy0 + dy;
    float w0=0.125f, w1=0.375f, w2=0.375f, w3=0.125f;
    if (oy == 0){ w0=0.0f; w1=3.0f/7.0f; w2=3.0f/7.0f; w3=1.0f/7.0f; }
    if (oy == 127){ w3=0.0f; w0=1.0f/7.0f; w1=3.0f/7.0f; w2=3.0f/7.0f; }
    vbuf[dy][x] = w0*cc[2*dy] + w1*cc[2*dy+1] + w2*cc[2*dy+2] + w3*cc[2*dy+3];
  }
  __syncthreads();

  float ssq = 0.f;
  _Float16* dst = tm + (size_t)t * HW + (size_t)oy0 * WO;
  #pragma unroll
  for (int i = 0; i < 8; ++i){
    int e = x + 256*i;                 // 0..2047
    int oy = e >> 7;                   // local output row 0..15
    int ox = e & 127;
    float w[4]; int ix[4];
    mkw128(ox, w, ix);
    float val = w[0]*vbuf[oy][ix[0]] + w[1]*vbuf[oy][ix[1]]
              + w[2]*vbuf[oy][ix[2]] + w[3]*vbuf[oy][ix[3]];
    dst[oy*WO + ox] = (_Float16)val;
    ssq += val*val;
  }
  for (int off=32; off; off>>=1) ssq += __shfl_xor(ssq, off);
  if ((x & 63) == 0) wred[x >> 6] = ssq;
  __syncthreads();
  if (x == 0) tqpart[c*NT + t] = wred[0]+wred[1]+wred[2]+wred[3];
}

// K3: MFMA fp16 GEMM  part[z][q][t] = sum_{k in slice z} sigmoid(A[q][k]) * Tm[t][k]
// 512 threads = 8 waves (2 row-groups x 4 col-groups of 16x80). BM=32, BN=320, BK=64.
// A loaded DIRECTLY from global into fragments (no LDS round-trip), 1-step reg prefetch.
// B double-buffered in LDS (2x40KB -> 2 blocks/CU, 400 blocks fully co-resident),
// staged by global_load_lds issued BEFORE compute; single s_barrier + vmcnt(4) per step.
// MFMA K-chain identical to r5/r6 -> num bit-identical.
__global__ __launch_bounds__(512, 3) void k_gemm(const float* __restrict__ A,
                                                 const _Float16* __restrict__ Bm,
                                                 float* __restrict__ part,
                                                 float* __restrict__ pqpart){
  __shared__ _Float16 Bs[2][BN*BK];    // 2 x 40 KB
  const int tid = threadIdx.x;
  const int lane = tid & 63;
  const int wid = tid >> 6;            // 0..7
  const int wr = wid >> 2;             // row group 0..1  (rows wr*16..wr*16+15)
  const int wc = wid & 3;              // col group 0..3  (cols wc*80..wc*80+79)
  const int id = blockIdx.x;
  const int z = id & 7;                // id%8 -> XCD-pinned K-slab
  const int q0 = (id >> 3) * BM;
  const int ks = z * KSLICE;

  // A fragment source: lane owns row q0 + wr*16 + (lane&15), k-chunk elems (lane>>4)*8
  const float* ap = A + (size_t)(q0 + wr*16 + (lane & 15)) * HW + ks + (lane >> 4) * 8;

  f32x4 acc[5];
  #pragma unroll
  for (int n = 0; n < 5; ++n) acc[n] = (f32x4){0.f,0.f,0.f,0.f};
  float pqs = 0.f;

  // ---- prologue: stage B(0), prefetch A(0) ----
  #pragma unroll
  for (int i = 0; i < 5; ++i){
    int g = i*512 + tid;               // 16B chunk 0..2559
    int row = g >> 3, s = g & 7;
    GLOAD_LDS16(Bm + (size_t)row*HW + ks + ((s ^ (row & 7)) * 8), &Bs[0][(size_t)g*8]);
  }
  float4 a0 = *(const float4*)(ap);
  float4 a1 = *(const float4*)(ap + 4);
  float4 a2 = *(const float4*)(ap + 32);
  float4 a3 = *(const float4*)(ap + 36);
  asm volatile("s_waitcnt vmcnt(0)" ::: "memory");
  __builtin_amdgcn_s_barrier();

  for (int kt = 0; kt < KTILES; ++kt){
    const int cur = kt & 1, nxt = cur ^ 1;
    // 1) stage B(kt+1) into the other buffer (hidden under compute below)
    if (kt + 1 < KTILES){
      #pragma unroll
      for (int i = 0; i < 5; ++i){
        int g = i*512 + tid;
        int row = g >> 3, s = g & 7;
        GLOAD_LDS16(Bm + (size_t)row*HW + ks + (kt+1)*BK + ((s ^ (row & 7)) * 8),
                    &Bs[nxt][(size_t)g*8]);
      }
    }
    // 2) prefetch A(kt+1) (issued after stages so vmcnt(4) leaves exactly these in flight)
    float4 b0, b1, b2, b3;
    if (kt + 1 < KTILES){
      const float* apn = ap + (kt+1)*BK;
      b0 = *(const float4*)(apn);
      b1 = *(const float4*)(apn + 4);
      b2 = *(const float4*)(apn + 32);
      b3 = *(const float4*)(apn + 36);
    }
    // 3) compute tile kt: kc=0 (a0,a1), kc=1 (a2,a3) — ascending K, chain as r5/r6
    {
      float s0 = sigfast(a0.x), s1 = sigfast(a0.y), s2 = sigfast(a0.z), s3 = sigfast(a0.w);
      float s4 = sigfast(a1.x), s5 = sigfast(a1.y), s6 = sigfast(a1.z), s7 = sigfast(a1.w);
      pqs += s0*s0 + s1*s1 + s2*s2 + s3*s3 + s4*s4 + s5*s5 + s6*s6 + s7*s7;
      half8v af = { (_Float16)s0, (_Float16)s1, (_Float16)s2, (_Float16)s3,
                    (_Float16)s4, (_Float16)s5, (_Float16)s6, (_Float16)s7 };
      #pragma unroll
      for (int n = 0; n < 5; ++n){
        int r = wc*80 + n*16 + (lane & 15);
        int s = 0*4 + (lane >> 4);
        half8v bf = *(const half8v*)&Bs[cur][r*BK + ((s ^ (r & 7)) * 8)];
        acc[n] = __builtin_amdgcn_mfma_f32_16x16x32_f16(af, bf, acc[n], 0, 0, 0);
      }
    }
    {
      float s0 = sigfast(a2.x), s1 = sigfast(a2.y), s2 = sigfast(a2.z), s3 = sigfast(a2.w);
      float s4 = sigfast(a3.x), s5 = sigfast(a3.y), s6 = sigfast(a3.z), s7 = sigfast(a3.w);
      pqs += s0*s0 + s1*s1 + s2*s2 + s3*s3 + s4*s4 + s5*s5 + s6*s6 + s7*s7;
      half8v af = { (_Float16)s0, (_Float16)s1, (_Float16)s2, (_Float16)s3,
                    (_Float16)s4, (_Float16)s5, (_Float16)s6, (_Float16)s7 };
      #pragma unroll
      for (int n = 0; n < 5; ++n){
        int r = wc*80 + n*16 + (lane & 15);
        int s = 1*4 + (lane >> 4);
        half8v bf = *(const half8v*)&Bs[cur][r*BK + ((s ^ (r & 7)) * 8)];
        acc[n] = __builtin_amdgcn_mfma_f32_16x16x32_f16(af, bf, acc[n], 0, 0, 0);
      }
    }
    // 4) wait only for the B stages (A prefetch floats across the barrier)
    asm volatile("s_waitcnt vmcnt(4)" ::: "memory");
    __builtin_amdgcn_s_barrier();
    if (kt + 1 < KTILES){ a0 = b0; a1 = b1; a2 = b2; a3 = b3; }
  }

  // write split-K partials (fp32): C/D layout col=lane&15, row=(lane>>4)*4+reg
  float* op = part + (size_t)z * (QT*NT);
  {
    int qb = q0 + wr*16 + (lane >> 4)*4;
    #pragma unroll
    for (int n = 0; n < 5; ++n){
      int t = wc*80 + n*16 + (lane & 15);
      #pragma unroll
      for (int r = 0; r < 4; ++r)
        op[(size_t)(qb + r)*NT + t] = acc[n][r];
    }
  }
  // pq partial: sigmoid computed redundantly per col-group; only wc==0 writes.
  // lane&15 = row, lane>>4 = k-chunk -> reduce across the 4 chunk lanes of each row.
  if (wc == 0){
    pqs += __shfl_xor(pqs, 16);
    pqs += __shfl_xor(pqs, 32);
    if (lane < 16) pqpart[z*QT + q0 + wr*16 + lane] = pqs;
  }
}

// K4: final cost C = dice^0.8 * prob^0.2 (reduces split-K partials of num, pq, tq)
__global__ __launch_bounds__(256) void k_cost(const float* __restrict__ part,
                                              const float* __restrict__ pqpart,
                                              const float* __restrict__ tqpart,
                                              const float* __restrict__ logits,
                                              const int* __restrict__ ids,
                                              float* __restrict__ Cout){
  int idx = blockIdx.x * 256 + threadIdx.x;
  int q = idx / NT;
  int t = idx - q * NT;
  float num = 0.f;
  #pragma unroll
  for (int s = 0; s < KSPLIT; ++s) num += part[(size_t)s * (QT*NT) + idx];
  num *= 2.0f;
  float pqv = 0.f;
  #pragma unroll
  for (int s = 0; s < KSPLIT; ++s) pqv += pqpart[s * QT + q];
  float tqv = 0.f;
  #pragma unroll
  for (int s = 0; s < 8; ++s) tqv += tqpart[s * NT + t];
  float den = pqv + tqv + 1e-4f;
  float dice = num / den;
  float prob = sigf(logits[q * NCLS + ids[t]]);
  Cout[idx] = powf(dice, 0.8f) * powf(prob, 0.2f);
}

// K5: Hungarian (JV / e-maxx with potentials), transposed: 20 rows (targets) x 100 cols (preds).
__global__ __launch_bounds__(64) void k_hung(const float* __restrict__ C,
                                             float* __restrict__ rows_out,
                                             float* __restrict__ cols_out){
  const int b = blockIdx.x;
  const int lane = threadIdx.x;
  __shared__ float negC[PI*NP];     // [i][j] = -C[b, j, b*PI + i]
  __shared__ double u[PI+1];
  __shared__ int p[NP+1];
  __shared__ int way[NP+1];
  for (int e = lane; e < PI*NP; e += 64){
    int i = e / NP, j = e - i*NP;
    negC[e] = -C[(size_t)(b*NP + j)*NT + (b*PI + i)];
  }
  if (lane <= PI) u[lane] = 0.0;
  for (int j = lane; j <= NP; j += 64){ p[j] = 0; way[j] = 0; }
  __syncthreads();
  const int jA = lane + 1;           // 1..64
  const int jB = lane + 65;          // 65..128
  const bool hasB = (jB <= NP);
  double vA = 0.0, vB = 0.0;
  const double INFD = 1e18;
  for (int i = 1; i <= PI; ++i){
    if (lane == 0) p[0] = i;
    __syncthreads();
    double mvA = INFD, mvB = INFD;
    bool usA = false, usB = false;
    int j0 = 0;
    int jbrk = 0;
    while (true){
      if (jA == j0) usA = true;
      if (hasB && jB == j0) usB = true;
      int i0 = p[j0];
      double ui0 = u[i0];
      double candA = INFD, candB = INFD;
      if (!usA){
        double cur = (double)negC[(i0-1)*NP + (jA-1)] - ui0 - vA;
        if (cur < mvA){ mvA = cur; way[jA] = j0; }
        candA = mvA;
      }
      if (hasB && !usB){
        double cur = (double)negC[(i0-1)*NP + (jB-1)] - ui0 - vB;
        if (cur < mvB){ mvB = cur; way[jB] = j0; }
        candB = mvB;
      }
      double bv; int bj;
      if (candB < candA){ bv = candB; bj = jB; } else { bv = candA; bj = jA; }
      for (int off = 32; off; off >>= 1){
        double ov = __shfl_xor(bv, off);
        int oj = __shfl_xor(bj, off);
        if (ov < bv || (ov == bv && oj < bj)){ bv = ov; bj = oj; }
      }
      const double delta = bv;
      if (usA){ int pj = p[jA]; u[pj] += delta; vA -= delta; }
      else mvA -= delta;
      if (hasB){
        if (usB){ int pj = p[jB]; u[pj] += delta; vB -= delta; }
        else mvB -= delta;
      }
      if (lane == 0) u[p[0]] += delta;   // virtual column 0 carries the new row
      __syncthreads();
      j0 = bj;
      if (p[j0] == 0){ jbrk = j0; break; }
    }
    __syncthreads();
    if (lane == 0){
      int j0a = jbrk;
      while (j0a){
        int jp = way[j0a];
        p[j0a] = p[jp];
        j0a = jp;
      }
    }
    __syncthreads();
  }
  if (lane == 0){
    int cnt = 0;
    for (int j = 1; j <= NP; ++j){
      int pi = p[j];
      if (pi != 0){
        rows_out[b*PI + cnt] = (float)(j - 1);   // prediction index, ascending
        cols_out[b*PI + cnt] = (float)(pi - 1);  // target index within image
        ++cnt;
      }
    }
  }
}

extern "C" void kernel_launch(void* const* d_in, const int* in_sizes, int n_in,
                              void* d_out, int out_size, void* d_ws, size_t ws_size,
                              hipStream_t stream){
  const float* pred_masks  = (const float*)d_in[0];
  const float* pred_logits = (const float*)d_in[1];
  const float* tgt_masks   = (const float*)d_in[2];
  const int*   tgt_ids     = (const int*)d_in[3];
  float* out = (float*)d_out;
  char* ws = (char*)d_ws;
  _Float16* Th  = (_Float16*)ws;                                    // 10.49 MB
  float* tqpart = (float*)(ws + (size_t)NT*HW*2);                   // 8*320 f32
  float* pqpart = (float*)(ws + (size_t)NT*HW*2 + 16384);           // 8*1600 f32
  float* part   = (float*)(ws + (size_t)NT*HW*2 + 16384 + 65536);   // 8*512000 f32 = 16.4 MB

  k_downsample<<<NT*8, 256, 0, stream>>>(tgt_masks, Th, tqpart);
  k_gemm<<<50*KSPLIT, 512, 0, stream>>>(pred_masks, Th, part, pqpart);
  k_cost<<<(QT*NT)/256, 256, 0, stream>>>(part, pqpart, tqpart, pred_logits, tgt_ids, out);
  k_hung<<<NB, 64, 0, stream>>>(out, out + (size_t)QT*NT, out + (size_t)QT*NT + NT);
}

// Round 8
// 125.763 us; speedup vs baseline: 1.2403x; 1.2403x over previous
//
#include <hip/hip_runtime.h>
#include <math.h>

#define NB 16          // images
#define NP 100         // predictions per image
#define NT 320         // total targets
#define NCLS 80        // classes
#define WO 128         // output mask width/height
#define HW 16384       // 128*128
#define QT 1600        // NB*NP
#define PI 20          // targets per image
#define KSPLIT 8
#define KSLICE 2048    // HW/KSPLIT  (same slice boundaries as r3/r5/r6/r7 -> bit-identical num)
#define BK 64
#define KTILES 32      // KSLICE/BK
#define SRC_W 256
#define BM 64
#define BN 160
#define CH 16          // output rows per downsample block

typedef _Float16 half8v __attribute__((ext_vector_type(8)));
typedef float f32x4 __attribute__((ext_vector_type(4)));

#define GLOAD_LDS16(gp, lp) __builtin_amdgcn_global_load_lds(                         \
    (const __attribute__((address_space(1))) void*)(gp),                              \
    (__attribute__((address_space(3))) void*)(lp), 16, 0, 0)

__device__ __forceinline__ float sigf(float x){ return 1.0f/(1.0f+expf(-x)); }
__device__ __forceinline__ float sigfast(float x){ return 1.0f/(1.0f+__expf(-x)); }

// jax.image.resize(linear, antialias=True) 2x-downsample weights, 256 -> 128
__device__ __forceinline__ void mkw128(int i, float* w, int* ix){
  int j0 = 2*i - 1;
  ix[0]=j0; ix[1]=j0+1; ix[2]=j0+2; ix[3]=j0+3;
  w[0]=0.125f; w[1]=0.375f; w[2]=0.375f; w[3]=0.125f;
  if (i == 0){ ix[0]=0; w[0]=0.0f; w[1]=3.0f/7.0f; w[2]=3.0f/7.0f; w[3]=1.0f/7.0f; }
  if (i == 127){ ix[3]=255; w[3]=0.0f; w[0]=1.0f/7.0f; w[1]=3.0f/7.0f; w[2]=3.0f/7.0f; }
}

// K1: separable downsample, one block per (target, 16-row output chunk).
__global__ __launch_bounds__(256) void k_downsample(const float* __restrict__ tgt,
                                                    _Float16* __restrict__ tm,
                                                    float* __restrict__ tqpart){
  const int blk = blockIdx.x;
  const int t = blk >> 3;
  const int c = blk & 7;               // chunk: output rows [c*16, c*16+16)
  const int x = threadIdx.x;           // input column 0..255
  const int oy0 = c * CH;
  const int r0 = 2*oy0 - 1;            // first needed input row (may be -1)
  const float* src = tgt + (size_t)t * (SRC_W*SRC_W);
  __shared__ float vbuf[CH][SRC_W];
  __shared__ float wred[4];

  float cc[34];
  #pragma unroll
  for (int li = 0; li < 34; ++li){
    int r = r0 + li; r = r < 0 ? 0 : (r > 255 ? 255 : r);
    cc[li] = src[r*SRC_W + x];
  }
  #pragma unroll
  for (int dy = 0; dy < CH; ++dy){
    int oy = oy0 + dy;
    float w0=0.125f, w1=0.375f, w2=0.375f, w3=0.125f;
    if (oy == 0){ w0=0.0f; w1=3.0f/7.0f; w2=3.0f/7.0f; w3=1.0f/7.0f; }
    if (oy == 127){ w3=0.0f; w0=1.0f/7.0f; w1=3.0f/7.0f; w2=3.0f/7.0f; }
    vbuf[dy][x] = w0*cc[2*dy] + w1*cc[2*dy+1] + w2*cc[2*dy+2] + w3*cc[2*dy+3];
  }
  __syncthreads();

  float ssq = 0.f;
  _Float16* dst = tm + (size_t)t * HW + (size_t)oy0 * WO;
  #pragma unroll
  for (int i = 0; i < 8; ++i){
    int e = x + 256*i;                 // 0..2047
    int oy = e >> 7;                   // local output row 0..15
    int ox = e & 127;
    float w[4]; int ix[4];
    mkw128(ox, w, ix);
    float val = w[0]*vbuf[oy][ix[0]] + w[1]*vbuf[oy][ix[1]]
              + w[2]*vbuf[oy][ix[2]] + w[3]*vbuf[oy][ix[3]];
    dst[oy*WO + ox] = (_Float16)val;
    ssq += val*val;
  }
  for (int off=32; off; off>>=1) ssq += __shfl_xor(ssq, off);
  if ((x & 63) == 0) wred[x >> 6] = ssq;
  __syncthreads();
  if (x == 0) tqpart[c*NT + t] = wred[0]+wred[1]+wred[2]+wred[3];
}

// K3: MFMA fp16 GEMM  part[z][q][t] = sum_{k in slice z} sigmoid(A[q][k]) * Tm[t][k]
// r3 tile (BM=64 x BN=160 x BK=64, grid 25x2x8) with:
//  - 512 threads / 8 waves (wave = 16x80, 10 MFMA/step) -> 2x TLP of r3
//  - double-buffered As+Bs (56 KB, 2 blocks/CU), ONE s_barrier per K-step
//  - stage B(kt+1) via global_load_lds + 2-deep A register prefetch;
//    s_waitcnt vmcnt(2) lgkmcnt(0) before the barrier (A prefetch floats across)
// Per-fragment MFMA operand chain identical to r3/r5/r6/r7 -> num bit-identical.
__global__ __launch_bounds__(512, 4) void k_gemm(const float* __restrict__ A,
                                                 const _Float16* __restrict__ Bm,
                                                 float* __restrict__ part,
                                                 float* __restrict__ pqpart){
  __shared__ _Float16 As[2][BM*BK];    // 2 x 8 KB
  __shared__ _Float16 Bs[2][BN*BK];    // 2 x 20 KB
  const int tid = threadIdx.x;
  const int lane = tid & 63;
  const int wid = tid >> 6;            // 0..7
  const int rg = wid >> 1;             // row group 0..3  (rows rg*16..+15)
  const int cg = wid & 1;              // col group 0..1  (cols cg*80..+79)
  const int q0 = blockIdx.x * BM;
  const int t0 = blockIdx.y * BN;
  const int z  = blockIdx.z;
  const int ks = z * KSLICE;

  // A-staging: row = tid>>3 (0..63), 8 floats at col (tid&7)*8
  const int ar = tid >> 3;
  const int ac8 = tid & 7;             // 8-col chunk index
  const float* ap = A + (size_t)(q0 + ar) * HW + ks + ac8*8;
  const int awoff = ar*BK + ((ac8 ^ (ar & 7)) * 8);

  f32x4 acc[5];
  #pragma unroll
  for (int n = 0; n < 5; ++n) acc[n] = (f32x4){0.f,0.f,0.f,0.f};
  float pqs = 0.f;

  // ---- prologue: stage B(0), sigmoid A(0) -> As[0], prefetch A(1) ----
  #pragma unroll
  for (int i = 0; i < 3; ++i){
    int g = i*512 + tid;               // 16B chunk 0..1279
    if (g < 1280){
      int row = g >> 3, s = g & 7;
      GLOAD_LDS16(Bm + (size_t)(t0 + row)*HW + ks + ((s ^ (row & 7)) * 8),
                  &Bs[0][(size_t)g*8]);
    }
  }
  {
    float4 v0 = *(const float4*)(ap);
    float4 v1 = *(const float4*)(ap + 4);
    float s0 = sigfast(v0.x), s1 = sigfast(v0.y), s2 = sigfast(v0.z), s3 = sigfast(v0.w);
    float s4 = sigfast(v1.x), s5 = sigfast(v1.y), s6 = sigfast(v1.z), s7 = sigfast(v1.w);
    pqs += s0*s0 + s1*s1 + s2*s2 + s3*s3 + s4*s4 + s5*s5 + s6*s6 + s7*s7;
    half8v hh = { (_Float16)s0, (_Float16)s1, (_Float16)s2, (_Float16)s3,
                  (_Float16)s4, (_Float16)s5, (_Float16)s6, (_Float16)s7 };
    *(half8v*)&As[0][awoff] = hh;
  }
  float4 aCur0 = *(const float4*)(ap + BK);
  float4 aCur1 = *(const float4*)(ap + BK + 4);
  asm volatile("s_waitcnt vmcnt(2) lgkmcnt(0)" ::: "memory");  // B(0)+As(0) ready; A(1) in flight
  __builtin_amdgcn_s_barrier();

  // ---- main loop: ONE barrier per K-step ----
  for (int kt = 0; kt < KTILES; ++kt){
    const int cur = kt & 1, nxt = cur ^ 1;
    // 1) stage B(kt+1) into the other buffer
    if (kt + 1 < KTILES){
      #pragma unroll
      for (int i = 0; i < 3; ++i){
        int g = i*512 + tid;
        if (g < 1280){
          int row = g >> 3, s = g & 7;
          GLOAD_LDS16(Bm + (size_t)(t0 + row)*HW + ks + (kt+1)*BK + ((s ^ (row & 7)) * 8),
                      &Bs[nxt][(size_t)g*8]);
        }
      }
    }
    // 2) prefetch A(kt+2) (issued after stages -> stays newest; floats across barrier)
    float4 aNext0, aNext1;
    if (kt + 2 < KTILES){
      const float* apn = ap + (kt+2)*BK;
      aNext0 = *(const float4*)(apn);
      aNext1 = *(const float4*)(apn + 4);
    }
    // 3) compute tile kt: ksub 0 then 1, ascending (chain as r3/r5/r6/r7)
    #pragma unroll
    for (int s = 0; s < 2; ++s){
      half8v af, bf[5];
      {
        int r = rg*16 + (lane & 15);
        int c = s*4 + (lane >> 4);
        af = *(const half8v*)&As[cur][r*BK + ((c ^ (r & 7)) * 8)];
      }
      #pragma unroll
      for (int n = 0; n < 5; ++n){
        int r = cg*80 + n*16 + (lane & 15);
        int c = s*4 + (lane >> 4);
        bf[n] = *(const half8v*)&Bs[cur][r*BK + ((c ^ (r & 7)) * 8)];
      }
      #pragma unroll
      for (int n = 0; n < 5; ++n)
        acc[n] = __builtin_amdgcn_mfma_f32_16x16x32_f16(af, bf[n], acc[n], 0, 0, 0);
    }
    // 4) sigmoid A(kt+1) (loaded one iteration ago) -> As[nxt]
    if (kt + 1 < KTILES){
      float s0 = sigfast(aCur0.x), s1 = sigfast(aCur0.y), s2 = sigfast(aCur0.z), s3 = sigfast(aCur0.w);
      float s4 = sigfast(aCur1.x), s5 = sigfast(aCur1.y), s6 = sigfast(aCur1.z), s7 = sigfast(aCur1.w);
      pqs += s0*s0 + s1*s1 + s2*s2 + s3*s3 + s4*s4 + s5*s5 + s6*s6 + s7*s7;
      half8v hh = { (_Float16)s0, (_Float16)s1, (_Float16)s2, (_Float16)s3,
                    (_Float16)s4, (_Float16)s5, (_Float16)s6, (_Float16)s7 };
      *(half8v*)&As[nxt][awoff] = hh;
      aCur0 = aNext0; aCur1 = aNext1;
    }
    // 5) drain B stages + As writes; leave the A(kt+2) prefetch in flight
    if (kt + 2 < KTILES){
      asm volatile("s_waitcnt vmcnt(2) lgkmcnt(0)" ::: "memory");
    } else {
      asm volatile("s_waitcnt vmcnt(0) lgkmcnt(0)" ::: "memory");
    }
    __builtin_amdgcn_s_barrier();
  }

  // write split-K partials (fp32): C/D layout col=lane&15, row=(lane>>4)*4+reg
  float* op = part + (size_t)z * (QT*NT);
  {
    int qb = q0 + rg*16 + (lane >> 4)*4;
    #pragma unroll
    for (int n = 0; n < 5; ++n){
      int t = t0 + cg*80 + n*16 + (lane & 15);
      #pragma unroll
      for (int r = 0; r < 4; ++r)
        op[(size_t)(qb + r)*NT + t] = acc[n][r];
    }
  }
  // pq partial: 8 threads per row; only the y=0 column-tile block writes (avoid 2x)
  if (blockIdx.y == 0){
    pqs += __shfl_xor(pqs, 1);
    pqs += __shfl_xor(pqs, 2);
    pqs += __shfl_xor(pqs, 4);
    if ((tid & 7) == 0) pqpart[z*QT + q0 + ar] = pqs;
  }
}

// K4: final cost C = dice^0.8 * prob^0.2 (reduces split-K partials of num, pq, tq)
__global__ __launch_bounds__(256) void k_cost(const float* __restrict__ part,
                                              const float* __restrict__ pqpart,
                                              const float* __restrict__ tqpart,
                                              const float* __restrict__ logits,
                                              const int* __restrict__ ids,
                                              float* __restrict__ Cout){
  int idx = blockIdx.x * 256 + threadIdx.x;
  int q = idx / NT;
  int t = idx - q * NT;
  float num = 0.f;
  #pragma unroll
  for (int s = 0; s < KSPLIT; ++s) num += part[(size_t)s * (QT*NT) + idx];
  num *= 2.0f;
  float pqv = 0.f;
  #pragma unroll
  for (int s = 0; s < KSPLIT; ++s) pqv += pqpart[s * QT + q];
  float tqv = 0.f;
  #pragma unroll
  for (int s = 0; s < 8; ++s) tqv += tqpart[s * NT + t];
  float den = pqv + tqv + 1e-4f;
  float dice = num / den;
  float prob = sigf(logits[q * NCLS + ids[t]]);
  Cout[idx] = powf(dice, 0.8f) * powf(prob, 0.2f);
}

// K5: Hungarian (JV / e-maxx with potentials), transposed: 20 rows (targets) x 100 cols (preds).
__global__ __launch_bounds__(64) void k_hung(const float* __restrict__ C,
                                             float* __restrict__ rows_out,
                                             float* __restrict__ cols_out){
  const int b = blockIdx.x;
  const int lane = threadIdx.x;
  __shared__ float negC[PI*NP];     // [i][j] = -C[b, j, b*PI + i]
  __shared__ double u[PI+1];
  __shared__ int p[NP+1];
  __shared__ int way[NP+1];
  for (int e = lane; e < PI*NP; e += 64){
    int i = e / NP, j = e - i*NP;
    negC[e] = -C[(size_t)(b*NP + j)*NT + (b*PI + i)];
  }
  if (lane <= PI) u[lane] = 0.0;
  for (int j = lane; j <= NP; j += 64){ p[j] = 0; way[j] = 0; }
  __syncthreads();
  const int jA = lane + 1;           // 1..64
  const int jB = lane + 65;          // 65..128
  const bool hasB = (jB <= NP);
  double vA = 0.0, vB = 0.0;
  const double INFD = 1e18;
  for (int i = 1; i <= PI; ++i){
    if (lane == 0) p[0] = i;
    __syncthreads();
    double mvA = INFD, mvB = INFD;
    bool usA = false, usB = false;
    int j0 = 0;
    int jbrk = 0;
    while (true){
      if (jA == j0) usA = true;
      if (hasB && jB == j0) usB = true;
      int i0 = p[j0];
      double ui0 = u[i0];
      double candA = INFD, candB = INFD;
      if (!usA){
        double cur = (double)negC[(i0-1)*NP + (jA-1)] - ui0 - vA;
        if (cur < mvA){ mvA = cur; way[jA] = j0; }
        candA = mvA;
      }
      if (hasB && !usB){
        double cur = (double)negC[(i0-1)*NP + (jB-1)] - ui0 - vB;
        if (cur < mvB){ mvB = cur; way[jB] = j0; }
        candB = mvB;
      }
      double bv; int bj;
      if (candB < candA){ bv = candB; bj = jB; } else { bv = candA; bj = jA; }
      for (int off = 32; off; off >>= 1){
        double ov = __shfl_xor(bv, off);
        int oj = __shfl_xor(bj, off);
        if (ov < bv || (ov == bv && oj < bj)){ bv = ov; bj = oj; }
      }
      const double delta = bv;
      if (usA){ int pj = p[jA]; u[pj] += delta; vA -= delta; }
      else mvA -= delta;
      if (hasB){
        if (usB){ int pj = p[jB]; u[pj] += delta; vB -= delta; }
        else mvB -= delta;
      }
      if (lane == 0) u[p[0]] += delta;   // virtual column 0 carries the new row
      __syncthreads();
      j0 = bj;
      if (p[j0] == 0){ jbrk = j0; break; }
    }
    __syncthreads();
    if (lane == 0){
      int j0a = jbrk;
      while (j0a){
        int jp = way[j0a];
        p[j0a] = p[jp];
        j0a = jp;
      }
    }
    __syncthreads();
  }
  if (lane == 0){
    int cnt = 0;
    for (int j = 1; j <= NP; ++j){
      int pi = p[j];
      if (pi != 0){
        rows_out[b*PI + cnt] = (float)(j - 1);   // prediction index, ascending
        cols_out[b*PI + cnt] = (float)(pi - 1);  // target index within image
        ++cnt;
      }
    }
  }
}

extern "C" void kernel_launch(void* const* d_in, const int* in_sizes, int n_in,
                              void* d_out, int out_size, void* d_ws, size_t ws_size,
                              hipStream_t stream){
  const float* pred_masks  = (const float*)d_in[0];
  const float* pred_logits = (const float*)d_in[1];
  const float* tgt_masks   = (const float*)d_in[2];
  const int*   tgt_ids     = (const int*)d_in[3];
  float* out = (float*)d_out;
  char* ws = (char*)d_ws;
  _Float16* Th  = (_Float16*)ws;                                    // 10.49 MB
  float* tqpart = (float*)(ws + (size_t)NT*HW*2);                   // 8*320 f32
  float* pqpart = (float*)(ws + (size_t)NT*HW*2 + 16384);           // 8*1600 f32
  float* part   = (float*)(ws + (size_t)NT*HW*2 + 16384 + 65536);   // 8*512000 f32 = 16.4 MB

  k_downsample<<<NT*8, 256, 0, stream>>>(tgt_masks, Th, tqpart);
  dim3 g(QT/BM, NT/BN, KSPLIT);
  k_gemm<<<g, 512, 0, stream>>>(pred_masks, Th, part, pqpart);
  k_cost<<<(QT*NT)/256, 256, 0, stream>>>(part, pqpart, tqpart, pred_logits, tgt_ids, out);
  k_hung<<<NB, 64, 0, stream>>>(out, out + (size_t)QT*NT, out + (size_t)QT*NT + NT);
}